// Round 2
// 4883.327 us; speedup vs baseline: 1.0640x; 1.0640x over previous
//
#include <hip/hip_runtime.h>
#include <math.h>

// B=32 S=512 H=2048 NH=8 HD=256.
// R4 == R3 resubmit (R3 bench died at container level — infra, no kernel verdict).
// All weights pre-converted fp32->bf16 (staged through dead d_out regions),
// gemm_bt staging via global_load_lds dwordx4 (m93->m97 ladder step).
// Inputs/output fp32; internal activations bf16 (MFMA), fp32 accum.
// Scratch: ws 128 MiB (RA/RB 64 MiB each); d_out (128 MiB fp32) doubles as
// scratch with a staged schedule:
//   t0:    WqkvB [48,72M)  WoutB [72,80M)          (converted at start)
//   attn:  Pc [0,32M)  VTc [32,48M)                (WqkvB live)
//   step7: R1 bf16 [0,64M)                          (WoutB live; Wqkv dead)
//   post7: Wff1B [64,96M)  Wff2B [96,128M)          (Wout dead after step 7)
//   ffn:   F1c [0,32M)                              (R1 dead after LN)
//   post:  WteB1/WteB2/WprB1/WprB2 [0,32M)          (F1c dead)
//   final: OUT fp32 overwrites everything.

typedef __bf16 bf16;
typedef __bf16 bf16x8 __attribute__((ext_vector_type(8)));
typedef float f32x4 __attribute__((ext_vector_type(4)));

#define Hdim 2048

// async global->LDS, 16B per lane. LDS dest must be wave-uniform base + lane*16.
#define GLOAD_LDS16(gp, lp)                                          \
  __builtin_amdgcn_global_load_lds(                                  \
      (const __attribute__((address_space(1))) void*)(gp),           \
      (__attribute__((address_space(3))) void*)(lp), 16, 0, 0)

// ---------------------------------------------------------------------------
// Batched GEMM: C[m,n] = act(scale*sum_k A[m,k]*W[n,k] + bias[n] + res[m,n])
// A,W: bf16 row-major [M,K]/[N,K]. C: bf16. bias fp32|null.
// res: fp32 (RF=1) / bf16 (RF=0) or null.
// Batch offsets (elements): ptr += (z/zd)*s1 + (z%zd)*s2.
// BM=BN=128, BK=64; 256 thr = 4 waves 2x2; 4x4 frags of 16x16x32 MFMA.
// Staging via global_load_lds_dwordx4: per thread 4 A-loads + 4 W-loads/K-step.
// ---------------------------------------------------------------------------
template <int RF>
__global__ __launch_bounds__(256)
void gemm_bt(const bf16* __restrict__ A, int lda, long sA1, long sA2, int zdA,
             const bf16* __restrict__ W, int ldw, long sW1, long sW2, int zdW,
             bf16* __restrict__ C, int ldc, long sC1, long sC2, int zdC,
             const float* __restrict__ bias,
             const void* __restrict__ resp, int ldr,
             int K, float scale, int act)
{
  __shared__ bf16 As[128 * 64];
  __shared__ bf16 Ws[128 * 64];
  const int tid = threadIdx.x;
  const int z = blockIdx.z;
  A += (size_t)(z / zdA) * sA1 + (size_t)(z % zdA) * sA2;
  W += (size_t)(z / zdW) * sW1 + (size_t)(z % zdW) * sW2;
  C += (size_t)(z / zdC) * sC1 + (size_t)(z % zdC) * sC2;
  const int m0 = blockIdx.y * 128, n0 = blockIdx.x * 128;
  const int sm = tid >> 3;          // staging row 0..31 (+32 per sweep)
  const int sk = (tid & 7) * 8;     // staging k-offset (elements)
  const int lane = tid & 63, quad = lane >> 4, lr = lane & 15;
  const int wid = tid >> 6, wm = wid >> 1, wn = wid & 1;

  f32x4 acc[4][4] = {};

  const bf16* Ag = A + (size_t)(m0 + sm) * lda + sk;
  const bf16* Wg = W + (size_t)(n0 + sm) * ldw + sk;
  // LDS dest: (s*2048 + tid*8) elems = s*4KiB + wave*1KiB + lane*16B  (linear)
  bf16* Ad = &As[tid * 8];
  bf16* Wd = &Ws[tid * 8];

  for (int k0 = 0; k0 < K; k0 += 64) {
#pragma unroll
    for (int s = 0; s < 4; ++s) {
      GLOAD_LDS16(Ag + (size_t)(s * 32) * lda + k0, Ad + s * 2048);
      GLOAD_LDS16(Wg + (size_t)(s * 32) * ldw + k0, Wd + s * 2048);
    }
    __syncthreads();   // emits s_waitcnt vmcnt(0) lgkmcnt(0) before s_barrier
#pragma unroll
    for (int kk = 0; kk < 64; kk += 32) {
      bf16x8 af[4], bfr[4];
#pragma unroll
      for (int i = 0; i < 4; ++i)
        af[i] = *(const bf16x8*)&As[(wm * 64 + i * 16 + lr) * 64 + kk + quad * 8];
#pragma unroll
      for (int j = 0; j < 4; ++j)
        bfr[j] = *(const bf16x8*)&Ws[(wn * 64 + j * 16 + lr) * 64 + kk + quad * 8];
#pragma unroll
      for (int i = 0; i < 4; ++i)
#pragma unroll
        for (int j = 0; j < 4; ++j)
          acc[i][j] = __builtin_amdgcn_mfma_f32_16x16x32_bf16(af[i], bfr[j], acc[i][j], 0, 0, 0);
    }
    __syncthreads();
  }

  float bj[4];
#pragma unroll
  for (int j = 0; j < 4; ++j)
    bj[j] = bias ? bias[n0 + wn * 64 + j * 16 + lr] : 0.0f;

#pragma unroll
  for (int i = 0; i < 4; ++i) {
#pragma unroll
    for (int r = 0; r < 4; ++r) {
      const int m = m0 + wm * 64 + i * 16 + quad * 4 + r;   // C/D: row = quad*4+reg
#pragma unroll
      for (int j = 0; j < 4; ++j) {
        const int n = n0 + wn * 64 + j * 16 + lr;           // C/D: col = lane&15
        float v = acc[i][j][r] * scale + bj[j];
        if (resp) {
          if (RF) v += ((const float*)resp)[(size_t)m * ldr + n];
          else    v += (float)((const bf16*)resp)[(size_t)m * ldr + n];
        }
        if (act == 1) v = fmaxf(v, 0.0f);
        else if (act == 2) v = 0.5f * v * (1.0f + erff(v * 0.70710678118654752f));
        C[(size_t)m * ldc + n] = (bf16)v;
      }
    }
  }
}

// fp32 -> bf16 bulk convert; 8 elements/thread
__global__ __launch_bounds__(256)
void cvt_w(const float* __restrict__ src, bf16* __restrict__ dst)
{
  const size_t i = ((size_t)blockIdx.x * 256 + threadIdx.x) * 8;
  float4 a = *(const float4*)&src[i];
  float4 b = *(const float4*)&src[i + 4];
  bf16x8 o;
  o[0] = (bf16)a.x; o[1] = (bf16)a.y; o[2] = (bf16)a.z; o[3] = (bf16)a.w;
  o[4] = (bf16)b.x; o[5] = (bf16)b.y; o[6] = (bf16)b.z; o[7] = (bf16)b.w;
  *(bf16x8*)&dst[i] = o;
}

// X(bf16) = emb(fp32) + pe(fp32)[idx] — one block per token row
__global__ __launch_bounds__(256)
void gather_pe(const float* __restrict__ emb, const int* __restrict__ idx,
               const float* __restrict__ pe, bf16* __restrict__ X)
{
  const int m = blockIdx.x;
  const int p = idx[m];
  const size_t off = (size_t)m * Hdim + threadIdx.x * 8;
  const size_t poff = (size_t)p * Hdim + threadIdx.x * 8;
  float4 e0 = *(const float4*)&emb[off];
  float4 e1 = *(const float4*)&emb[off + 4];
  float4 q0 = *(const float4*)&pe[poff];
  float4 q1 = *(const float4*)&pe[poff + 4];
  bf16x8 o;
  o[0] = (bf16)(e0.x + q0.x); o[1] = (bf16)(e0.y + q0.y);
  o[2] = (bf16)(e0.z + q0.z); o[3] = (bf16)(e0.w + q0.w);
  o[4] = (bf16)(e1.x + q1.x); o[5] = (bf16)(e1.y + q1.y);
  o[6] = (bf16)(e1.z + q1.z); o[7] = (bf16)(e1.w + q1.w);
  *(bf16x8*)&X[off] = o;
}

// row-softmax over 512 cols in place (bf16); one wave per row
__global__ __launch_bounds__(256)
void softmax_rows(bf16* __restrict__ P)
{
  const int lane = threadIdx.x & 63;
  const size_t row = (size_t)blockIdx.x * 4 + (threadIdx.x >> 6);
  bf16* p = P + row * 512 + lane * 8;
  bf16x8 v = *(const bf16x8*)p;
  float x[8], mx = -1e30f;
#pragma unroll
  for (int j = 0; j < 8; ++j) { x[j] = (float)v[j]; mx = fmaxf(mx, x[j]); }
#pragma unroll
  for (int o = 32; o; o >>= 1) mx = fmaxf(mx, __shfl_xor(mx, o));
  float s = 0.0f;
#pragma unroll
  for (int j = 0; j < 8; ++j) { x[j] = expf(x[j] - mx); s += x[j]; }
#pragma unroll
  for (int o = 32; o; o >>= 1) s += __shfl_xor(s, o);
  const float inv = 1.0f / s;
  bf16x8 ov;
#pragma unroll
  for (int j = 0; j < 8; ++j) ov[j] = (bf16)(x[j] * inv);
  *(bf16x8*)p = ov;
}

// per-(b_local,h) transpose V[512,256] (bf16, row stride 6144 in QKVc) -> VT[256,512]
__global__ __launch_bounds__(256)
void transpose_v(const bf16* __restrict__ qkv, bf16* __restrict__ vt)
{
  const int z = blockIdx.z, b = z >> 3, h = z & 7;
  const unsigned short* V =
      (const unsigned short*)qkv + (size_t)b * 512 * 6144 + 4096 + h * 256;
  unsigned short* out = (unsigned short*)vt + (size_t)z * 256 * 512;
  const int d0 = blockIdx.x * 64, k0 = blockIdx.y * 64;
  __shared__ unsigned short t[64 * 65];
  const int r = threadIdx.x >> 3;
  const int c8 = (threadIdx.x & 7) * 8;
#pragma unroll
  for (int pass = 0; pass < 2; ++pass) {
    const int rr = r + pass * 32;
    uint4 u = *(const uint4*)(V + (size_t)(k0 + rr) * 6144 + d0 + c8);
    const unsigned short* ep = (const unsigned short*)&u;
#pragma unroll
    for (int j = 0; j < 8; ++j) t[(c8 + j) * 65 + rr] = ep[j];
  }
  __syncthreads();
#pragma unroll
  for (int pass = 0; pass < 2; ++pass) {
    const int dr = r + pass * 32;
    unsigned short e[8];
#pragma unroll
    for (int j = 0; j < 8; ++j) e[j] = t[dr * 65 + c8 + j];
    *(uint4*)(out + (size_t)(d0 + dr) * 512 + k0 + c8) = *(const uint4*)e;
  }
}

// LayerNorm over H=2048: bf16 src -> bf16 dst, fp32 g/b; one block per row
__global__ __launch_bounds__(256)
void ln_rows(const bf16* __restrict__ src, const float* __restrict__ g,
             const float* __restrict__ b, bf16* __restrict__ dst)
{
  const size_t off = (size_t)blockIdx.x * Hdim + threadIdx.x * 8;
  bf16x8 v = *(const bf16x8*)&src[off];
  float x[8], s = 0.0f, ss = 0.0f;
#pragma unroll
  for (int j = 0; j < 8; ++j) { x[j] = (float)v[j]; s += x[j]; ss += x[j] * x[j]; }
  __shared__ float red[8];
#pragma unroll
  for (int o = 32; o; o >>= 1) { s += __shfl_xor(s, o); ss += __shfl_xor(ss, o); }
  const int w = threadIdx.x >> 6;
  if ((threadIdx.x & 63) == 0) { red[w] = s; red[4 + w] = ss; }
  __syncthreads();
  s = red[0] + red[1] + red[2] + red[3];
  ss = red[4] + red[5] + red[6] + red[7];
  const float mean = s * (1.0f / Hdim);
  const float var = ss * (1.0f / Hdim) - mean * mean;
  const float rstd = rsqrtf(var + 1e-5f);
  float4 g0 = *(const float4*)&g[threadIdx.x * 8];
  float4 g1 = *(const float4*)&g[threadIdx.x * 8 + 4];
  float4 b0 = *(const float4*)&b[threadIdx.x * 8];
  float4 b1 = *(const float4*)&b[threadIdx.x * 8 + 4];
  const float gg[8] = {g0.x, g0.y, g0.z, g0.w, g1.x, g1.y, g1.z, g1.w};
  const float bb[8] = {b0.x, b0.y, b0.z, b0.w, b1.x, b1.y, b1.z, b1.w};
  bf16x8 ov;
#pragma unroll
  for (int j = 0; j < 8; ++j)
    ov[j] = (bf16)(((x[j] - mean) * rstd) * gg[j] + bb[j]);
  *(bf16x8*)&dst[off] = ov;
}

// OUT(fp32) = x / max(||x||_2, 1e-12) per row; bf16 src
__global__ __launch_bounds__(256)
void l2norm_rows(const bf16* __restrict__ src, float* __restrict__ dst)
{
  const size_t off = (size_t)blockIdx.x * Hdim + threadIdx.x * 8;
  bf16x8 v = *(const bf16x8*)&src[off];
  float x[8], ss = 0.0f;
#pragma unroll
  for (int j = 0; j < 8; ++j) { x[j] = (float)v[j]; ss += x[j] * x[j]; }
  __shared__ float red[4];
#pragma unroll
  for (int o = 32; o; o >>= 1) ss += __shfl_xor(ss, o);
  const int w = threadIdx.x >> 6;
  if ((threadIdx.x & 63) == 0) red[w] = ss;
  __syncthreads();
  ss = red[0] + red[1] + red[2] + red[3];
  const float inv = 1.0f / fmaxf(sqrtf(ss), 1e-12f);
  float4 o0, o1;
  o0.x = x[0] * inv; o0.y = x[1] * inv; o0.z = x[2] * inv; o0.w = x[3] * inv;
  o1.x = x[4] * inv; o1.y = x[5] * inv; o1.z = x[6] * inv; o1.w = x[7] * inv;
  *(float4*)&dst[off] = o0;
  *(float4*)&dst[off + 4] = o1;
}

// ---------------------------------------------------------------------------
extern "C" void kernel_launch(void* const* d_in, const int* in_sizes, int n_in,
                              void* d_out, int out_size, void* d_ws, size_t ws_size,
                              hipStream_t stream)
{
  const float* emb  = (const float*)d_in[0];
  const int*   tix  = (const int*)d_in[1];
  const float* pe   = (const float*)d_in[2];
  const float* Wqkv = (const float*)d_in[3];
  const float* Bqkv = (const float*)d_in[4];
  const float* Wout = (const float*)d_in[5];
  const float* Bout = (const float*)d_in[6];
  const float* ln1g = (const float*)d_in[7];
  const float* ln1b = (const float*)d_in[8];
  const float* Wff1 = (const float*)d_in[9];
  const float* Bff1 = (const float*)d_in[10];
  const float* Wff2 = (const float*)d_in[11];
  const float* Bff2 = (const float*)d_in[12];
  const float* ln2g = (const float*)d_in[13];
  const float* ln2b = (const float*)d_in[14];
  const float* Wte1 = (const float*)d_in[15];
  const float* Bte1 = (const float*)d_in[16];
  const float* Wte2 = (const float*)d_in[17];
  const float* Bte2 = (const float*)d_in[18];
  const float* Wpr1 = (const float*)d_in[19];
  const float* Bpr1 = (const float*)d_in[20];
  const float* Wpr2 = (const float*)d_in[21];
  const float* Bpr2 = (const float*)d_in[22];
  float* OUT = (float*)d_out;

  char* w = (char*)d_ws;
  bf16* RA   = (bf16*)(w);                 // 64 MiB
  bf16* RB   = (bf16*)(w + (64u << 20));   // 64 MiB
  bf16* QKVc = RB;
  char* ob   = (char*)d_out;
  bf16* Pc   = (bf16*)(ob);                // attn scores   [0,32M)
  bf16* VTc  = (bf16*)(ob + (32u << 20));  // V^T           [32,48M)
  bf16* R1   = (bf16*)(ob);                // attn residual [0,64M)
  bf16* F1c  = (bf16*)(ob);                // FFN hidden    [0,32M)
  // staged bf16 weight homes in d_out (see schedule at top)
  bf16* WqkvB = (bf16*)(ob + (48u << 20));
  bf16* WoutB = (bf16*)(ob + (72u << 20));
  bf16* Wff1B = (bf16*)(ob + (64u << 20));
  bf16* Wff2B = (bf16*)(ob + (96u << 20));
  bf16* WteB1 = (bf16*)(ob);
  bf16* WteB2 = (bf16*)(ob + (8u << 20));
  bf16* WprB1 = (bf16*)(ob + (16u << 20));
  bf16* WprB2 = (bf16*)(ob + (24u << 20));

  // 0. convert attention weights (d_out [48,80M) free until step 7 / FFN)
  cvt_w<<<6144, 256, 0, stream>>>(Wqkv, WqkvB);   // 6144x2048
  cvt_w<<<2048, 256, 0, stream>>>(Wout, WoutB);   // 2048x2048

  // 1. X = emb + pe[idx]
  gather_pe<<<16384, 256, 0, stream>>>(emb, tix, pe, RA);

  // 2-6. attention: 4 chunks of 8 batches (4096 rows, 64 (b,h) pairs each)
  for (int c = 0; c < 4; ++c) {
    const bf16* Xc = RA + (size_t)c * 4096 * 2048;
    bf16* Oc = RA + (size_t)c * 4096 * 2048;   // O rows alias dead X rows

    // QKVc = Xc @ Wqkv^T + Bqkv   [4096,6144]
    gemm_bt<0><<<dim3(48, 32, 1), 256, 0, stream>>>(
        Xc, 2048, 0, 0, 1, WqkvB, 2048, 0, 0, 1, QKVc, 6144, 0, 0, 1,
        Bqkv, nullptr, 0, 2048, 1.0f, 0);

    // Pc[z] = Q K^T / 16,  z = b_local*8 + h
    gemm_bt<0><<<dim3(4, 4, 64), 256, 0, stream>>>(
        QKVc, 6144, 3145728L, 256, 8,
        QKVc + 2048, 6144, 3145728L, 256, 8,
        Pc, 512, 262144L, 0, 1,
        nullptr, nullptr, 0, 256, 0.0625f, 0);

    softmax_rows<<<8192, 256, 0, stream>>>(Pc);

    transpose_v<<<dim3(4, 8, 64), 256, 0, stream>>>(QKVc, VTc);

    // Oc = Pc @ V
    gemm_bt<0><<<dim3(2, 4, 64), 256, 0, stream>>>(
        Pc, 512, 262144L, 0, 1,
        VTc, 512, 131072L, 0, 1,
        Oc, 2048, 1048576L, 256, 8,
        nullptr, nullptr, 0, 512, 1.0f, 0);
  }

  // 7. R1 = O @ Wout^T + Bout + emb(fp32 residual)   (R1 in d_out scratch)
  gemm_bt<1><<<dim3(16, 128, 1), 256, 0, stream>>>(
      RA, 2048, 0, 0, 1, WoutB, 2048, 0, 0, 1, R1, 2048, 0, 0, 1,
      Bout, emb, 2048, 2048, 1.0f, 0);

  // 7b. convert FFN weights into [64,128M) (Wout/Wqkv homes now dead)
  cvt_w<<<8192, 256, 0, stream>>>(Wff1, Wff1B);   // 8192x2048
  cvt_w<<<8192, 256, 0, stream>>>(Wff2, Wff2B);   // 2048x8192

  // 8. H1 = LN(R1) -> RA (O dead)
  ln_rows<<<16384, 256, 0, stream>>>(R1, ln1g, ln1b, RA);

  // 9-10. FFN in 8 row-chunks of 2048 rows; F1c in d_out (R1 dead); R2 -> RB
  for (int f = 0; f < 8; ++f) {
    const bf16* H1f = RA + (size_t)f * 2048 * 2048;
    bf16* R2f = RB + (size_t)f * 2048 * 2048;
    gemm_bt<0><<<dim3(64, 16, 1), 256, 0, stream>>>(
        H1f, 2048, 0, 0, 1, Wff1B, 2048, 0, 0, 1, F1c, 8192, 0, 0, 1,
        Bff1, nullptr, 0, 2048, 1.0f, 2);
    gemm_bt<0><<<dim3(16, 16, 1), 256, 0, stream>>>(
        F1c, 8192, 0, 0, 1, Wff2B, 8192, 0, 0, 1, R2f, 2048, 0, 0, 1,
        Bff2, H1f, 2048, 8192, 1.0f, 0);
  }

  // 10b. convert te/pr weights into [0,32M) (F1c dead)
  cvt_w<<<2048, 256, 0, stream>>>(Wte1, WteB1);
  cvt_w<<<2048, 256, 0, stream>>>(Wte2, WteB2);
  cvt_w<<<2048, 256, 0, stream>>>(Wpr1, WprB1);
  cvt_w<<<2048, 256, 0, stream>>>(Wpr2, WprB2);

  // 11. H2 = LN(R2) -> RA (H1 dead)
  ln_rows<<<16384, 256, 0, stream>>>(RB, ln2g, ln2b, RA);

  // 12. TM = relu(H2 @ Wte1^T + Bte1) -> RB
  gemm_bt<0><<<dim3(16, 128, 1), 256, 0, stream>>>(
      RA, 2048, 0, 0, 1, WteB1, 2048, 0, 0, 1, RB, 2048, 0, 0, 1,
      Bte1, nullptr, 0, 2048, 1.0f, 1);

  // 13. TE = TM @ Wte2^T + Bte2 -> RA
  gemm_bt<0><<<dim3(16, 128, 1), 256, 0, stream>>>(
      RB, 2048, 0, 0, 1, WteB2, 2048, 0, 0, 1, RA, 2048, 0, 0, 1,
      Bte2, nullptr, 0, 2048, 1.0f, 0);

  // 14. PM = relu(TE @ Wpr1^T + Bpr1) -> RB
  gemm_bt<0><<<dim3(16, 128, 1), 256, 0, stream>>>(
      RA, 2048, 0, 0, 1, WprB1, 2048, 0, 0, 1, RB, 2048, 0, 0, 1,
      Bpr1, nullptr, 0, 2048, 1.0f, 1);

  // 15. PR = PM @ Wpr2^T + Bpr2 -> RA
  gemm_bt<0><<<dim3(16, 128, 1), 256, 0, stream>>>(
      RB, 2048, 0, 0, 1, WprB2, 2048, 0, 0, 1, RA, 2048, 0, 0, 1,
      Bpr2, nullptr, 0, 2048, 1.0f, 0);

  // 16. OUT(fp32) = l2norm(PR)  (weights in d_out dead; full overwrite)
  l2norm_rows<<<16384, 256, 0, stream>>>(RA, OUT);
}

// Round 3
// 4113.417 us; speedup vs baseline: 1.2631x; 1.1872x over previous
//
#include <hip/hip_runtime.h>
#include <math.h>

// B=32 S=512 H=2048 NH=8 HD=256.
// R5: gemm_bt restructured to 2-phase prefetch (explicit LDS double-buffer,
// ONE __syncthreads per K-step; next tile's global_load_lds issued BEFORE
// current tile's MFMAs so the barrier's vmcnt(0) drain lands after compute).
// Plus: read-side XOR bank-swizzle realized via pre-swizzled GLOBAL source
// (rule #21: gload_lds dest stays linear; LDS[r][s] = G[r][s^(r&7)]), and
// XCD-chunked block swizzle (all grids nwg%8==0 -> bijective).
// Weights pre-converted fp32->bf16 (staged through dead d_out regions).
// Scratch schedule unchanged from R4 (see kernel_launch).

typedef __bf16 bf16;
typedef __bf16 bf16x8 __attribute__((ext_vector_type(8)));
typedef float f32x4 __attribute__((ext_vector_type(4)));

#define Hdim 2048

// async global->LDS, 16B per lane. LDS dest must be wave-uniform base + lane*16.
#define GLOAD_LDS16(gp, lp)                                          \
  __builtin_amdgcn_global_load_lds(                                  \
      (const __attribute__((address_space(1))) void*)(gp),           \
      (__attribute__((address_space(3))) void*)(lp), 16, 0, 0)

// ---------------------------------------------------------------------------
// Batched GEMM: C[m,n] = act(scale*sum_k A[m,k]*W[n,k] + bias[n] + res[m,n])
// A,W: bf16 row-major [M,K]/[N,K]. C: bf16. bias fp32|null.
// res: fp32 (RF=1) / bf16 (RF=0) or null.
// Batch offsets (elements): ptr += (z/zd)*s1 + (z%zd)*s2.
// BM=BN=128, BK=64; 256 thr = 4 waves 2x2; 4x4 frags of 16x16x32 MFMA.
// LDS layout per tile row r (64 bf16 = 8 slots of 16B): slot s holds global
// slot s^(r&7)  (write: thread fetches G slot (tid&7)^(sm&7) into linear LDS;
// read: slot (quad|4*kk)^(lr&7)). Breaks the 16-way same-bank read conflict.
// ---------------------------------------------------------------------------
template <int RF>
__global__ __launch_bounds__(256)
void gemm_bt(const bf16* __restrict__ A, int lda, long sA1, long sA2, int zdA,
             const bf16* __restrict__ W, int ldw, long sW1, long sW2, int zdW,
             bf16* __restrict__ C, int ldc, long sC1, long sC2, int zdC,
             const float* __restrict__ bias,
             const void* __restrict__ resp, int ldr,
             int K, float scale, int act)
{
  __shared__ bf16 As[2][128 * 64];
  __shared__ bf16 Ws[2][128 * 64];
  const int tid = threadIdx.x;
  const int z = blockIdx.z;
  A += (size_t)(z / zdA) * sA1 + (size_t)(z % zdA) * sA2;
  W += (size_t)(z / zdW) * sW1 + (size_t)(z % zdW) * sW2;
  C += (size_t)(z / zdC) * sC1 + (size_t)(z % zdC) * sC2;

  // XCD-chunked swizzle of the (x,y) grid plane (nwg % 8 == 0 at every call
  // site -> bijective). Consecutive swizzled ids stay on one XCD's L2.
  const int nwg = gridDim.x * gridDim.y;
  int bid = blockIdx.y * gridDim.x + blockIdx.x;
  bid = (bid & 7) * (nwg >> 3) + (bid >> 3);
  const int m0 = (bid / gridDim.x) * 128, n0 = (bid % gridDim.x) * 128;

  const int sm = tid >> 3;                        // staging row 0..31 (+32/sweep)
  const int swz = ((tid & 7) ^ (sm & 7)) * 8;     // pre-swizzled global slot
  const int lane = tid & 63, quad = lane >> 4, lr = lane & 15;
  const int wid = tid >> 6, wm = wid >> 1, wn = wid & 1;
  const int rx = lr & 7;
  const int so0 = ((quad      ) ^ rx) * 8;        // LDS slot elems, kk=0
  const int so1 = ((quad | 4) ^ rx) * 8;          // LDS slot elems, kk=32

  f32x4 acc[4][4] = {};

  const bf16* Ag = A + (size_t)(m0 + sm) * lda + swz;
  const bf16* Wg = W + (size_t)(n0 + sm) * ldw + swz;

  const int nt = K >> 6;
  // prologue: stage tile 0 into buffer 0
#pragma unroll
  for (int s = 0; s < 4; ++s) {
    GLOAD_LDS16(Ag + (size_t)(s * 32) * lda, &As[0][s * 2048 + tid * 8]);
    GLOAD_LDS16(Wg + (size_t)(s * 32) * ldw, &Ws[0][s * 2048 + tid * 8]);
  }
  __syncthreads();   // vmcnt(0) drain: buffer 0 ready

  for (int t = 0; t < nt; ++t) {
    const int cur = t & 1;
    if (t + 1 < nt) {            // prefetch next tile into the other buffer
      const int k0 = (t + 1) << 6;
#pragma unroll
      for (int s = 0; s < 4; ++s) {
        GLOAD_LDS16(Ag + (size_t)(s * 32) * lda + k0, &As[cur ^ 1][s * 2048 + tid * 8]);
        GLOAD_LDS16(Wg + (size_t)(s * 32) * ldw + k0, &Ws[cur ^ 1][s * 2048 + tid * 8]);
      }
    }
    const bf16* Ab = As[cur];
    const bf16* Wb = Ws[cur];
#pragma unroll
    for (int kk = 0; kk < 2; ++kk) {
      const int so = kk ? so1 : so0;
      bf16x8 af[4], bfr[4];
#pragma unroll
      for (int i = 0; i < 4; ++i)
        af[i] = *(const bf16x8*)&Ab[(wm * 64 + i * 16 + lr) * 64 + so];
#pragma unroll
      for (int j = 0; j < 4; ++j)
        bfr[j] = *(const bf16x8*)&Wb[(wn * 64 + j * 16 + lr) * 64 + so];
#pragma unroll
      for (int i = 0; i < 4; ++i)
#pragma unroll
        for (int j = 0; j < 4; ++j)
          acc[i][j] = __builtin_amdgcn_mfma_f32_16x16x32_bf16(af[i], bfr[j], acc[i][j], 0, 0, 0);
    }
    __syncthreads();  // drains vmcnt(0): prefetched buffer ready; cur reusable
  }

  float bj[4];
#pragma unroll
  for (int j = 0; j < 4; ++j)
    bj[j] = bias ? bias[n0 + wn * 64 + j * 16 + lr] : 0.0f;

#pragma unroll
  for (int i = 0; i < 4; ++i) {
#pragma unroll
    for (int r = 0; r < 4; ++r) {
      const int m = m0 + wm * 64 + i * 16 + quad * 4 + r;   // C/D: row = quad*4+reg
#pragma unroll
      for (int j = 0; j < 4; ++j) {
        const int n = n0 + wn * 64 + j * 16 + lr;           // C/D: col = lane&15
        float v = acc[i][j][r] * scale + bj[j];
        if (resp) {
          if (RF) v += ((const float*)resp)[(size_t)m * ldr + n];
          else    v += (float)((const bf16*)resp)[(size_t)m * ldr + n];
        }
        if (act == 1) v = fmaxf(v, 0.0f);
        else if (act == 2) v = 0.5f * v * (1.0f + erff(v * 0.70710678118654752f));
        C[(size_t)m * ldc + n] = (bf16)v;
      }
    }
  }
}

// fp32 -> bf16 bulk convert; 8 elements/thread
__global__ __launch_bounds__(256)
void cvt_w(const float* __restrict__ src, bf16* __restrict__ dst)
{
  const size_t i = ((size_t)blockIdx.x * 256 + threadIdx.x) * 8;
  float4 a = *(const float4*)&src[i];
  float4 b = *(const float4*)&src[i + 4];
  bf16x8 o;
  o[0] = (bf16)a.x; o[1] = (bf16)a.y; o[2] = (bf16)a.z; o[3] = (bf16)a.w;
  o[4] = (bf16)b.x; o[5] = (bf16)b.y; o[6] = (bf16)b.z; o[7] = (bf16)b.w;
  *(bf16x8*)&dst[i] = o;
}

// X(bf16) = emb(fp32) + pe(fp32)[idx] — one block per token row
__global__ __launch_bounds__(256)
void gather_pe(const float* __restrict__ emb, const int* __restrict__ idx,
               const float* __restrict__ pe, bf16* __restrict__ X)
{
  const int m = blockIdx.x;
  const int p = idx[m];
  const size_t off = (size_t)m * Hdim + threadIdx.x * 8;
  const size_t poff = (size_t)p * Hdim + threadIdx.x * 8;
  float4 e0 = *(const float4*)&emb[off];
  float4 e1 = *(const float4*)&emb[off + 4];
  float4 q0 = *(const float4*)&pe[poff];
  float4 q1 = *(const float4*)&pe[poff + 4];
  bf16x8 o;
  o[0] = (bf16)(e0.x + q0.x); o[1] = (bf16)(e0.y + q0.y);
  o[2] = (bf16)(e0.z + q0.z); o[3] = (bf16)(e0.w + q0.w);
  o[4] = (bf16)(e1.x + q1.x); o[5] = (bf16)(e1.y + q1.y);
  o[6] = (bf16)(e1.z + q1.z); o[7] = (bf16)(e1.w + q1.w);
  *(bf16x8*)&X[off] = o;
}

// row-softmax over 512 cols in place (bf16); one wave per row
__global__ __launch_bounds__(256)
void softmax_rows(bf16* __restrict__ P)
{
  const int lane = threadIdx.x & 63;
  const size_t row = (size_t)blockIdx.x * 4 + (threadIdx.x >> 6);
  bf16* p = P + row * 512 + lane * 8;
  bf16x8 v = *(const bf16x8*)p;
  float x[8], mx = -1e30f;
#pragma unroll
  for (int j = 0; j < 8; ++j) { x[j] = (float)v[j]; mx = fmaxf(mx, x[j]); }
#pragma unroll
  for (int o = 32; o; o >>= 1) mx = fmaxf(mx, __shfl_xor(mx, o));
  float s = 0.0f;
#pragma unroll
  for (int j = 0; j < 8; ++j) { x[j] = expf(x[j] - mx); s += x[j]; }
#pragma unroll
  for (int o = 32; o; o >>= 1) s += __shfl_xor(s, o);
  const float inv = 1.0f / s;
  bf16x8 ov;
#pragma unroll
  for (int j = 0; j < 8; ++j) ov[j] = (bf16)(x[j] * inv);
  *(bf16x8*)p = ov;
}

// per-(b_local,h) transpose V[512,256] (bf16, row stride 6144 in QKVc) -> VT[256,512]
__global__ __launch_bounds__(256)
void transpose_v(const bf16* __restrict__ qkv, bf16* __restrict__ vt)
{
  const int z = blockIdx.z, b = z >> 3, h = z & 7;
  const unsigned short* V =
      (const unsigned short*)qkv + (size_t)b * 512 * 6144 + 4096 + h * 256;
  unsigned short* out = (unsigned short*)vt + (size_t)z * 256 * 512;
  const int d0 = blockIdx.x * 64, k0 = blockIdx.y * 64;
  __shared__ unsigned short t[64 * 65];
  const int r = threadIdx.x >> 3;
  const int c8 = (threadIdx.x & 7) * 8;
#pragma unroll
  for (int pass = 0; pass < 2; ++pass) {
    const int rr = r + pass * 32;
    uint4 u = *(const uint4*)(V + (size_t)(k0 + rr) * 6144 + d0 + c8);
    const unsigned short* ep = (const unsigned short*)&u;
#pragma unroll
    for (int j = 0; j < 8; ++j) t[(c8 + j) * 65 + rr] = ep[j];
  }
  __syncthreads();
#pragma unroll
  for (int pass = 0; pass < 2; ++pass) {
    const int dr = r + pass * 32;
    unsigned short e[8];
#pragma unroll
    for (int j = 0; j < 8; ++j) e[j] = t[dr * 65 + c8 + j];
    *(uint4*)(out + (size_t)(d0 + dr) * 512 + k0 + c8) = *(const uint4*)e;
  }
}

// LayerNorm over H=2048: bf16 src -> bf16 dst, fp32 g/b; one block per row
__global__ __launch_bounds__(256)
void ln_rows(const bf16* __restrict__ src, const float* __restrict__ g,
             const float* __restrict__ b, bf16* __restrict__ dst)
{
  const size_t off = (size_t)blockIdx.x * Hdim + threadIdx.x * 8;
  bf16x8 v = *(const bf16x8*)&src[off];
  float x[8], s = 0.0f, ss = 0.0f;
#pragma unroll
  for (int j = 0; j < 8; ++j) { x[j] = (float)v[j]; s += x[j]; ss += x[j] * x[j]; }
  __shared__ float red[8];
#pragma unroll
  for (int o = 32; o; o >>= 1) { s += __shfl_xor(s, o); ss += __shfl_xor(ss, o); }
  const int w = threadIdx.x >> 6;
  if ((threadIdx.x & 63) == 0) { red[w] = s; red[4 + w] = ss; }
  __syncthreads();
  s = red[0] + red[1] + red[2] + red[3];
  ss = red[4] + red[5] + red[6] + red[7];
  const float mean = s * (1.0f / Hdim);
  const float var = ss * (1.0f / Hdim) - mean * mean;
  const float rstd = rsqrtf(var + 1e-5f);
  float4 g0 = *(const float4*)&g[threadIdx.x * 8];
  float4 g1 = *(const float4*)&g[threadIdx.x * 8 + 4];
  float4 b0 = *(const float4*)&b[threadIdx.x * 8];
  float4 b1 = *(const float4*)&b[threadIdx.x * 8 + 4];
  const float gg[8] = {g0.x, g0.y, g0.z, g0.w, g1.x, g1.y, g1.z, g1.w};
  const float bb[8] = {b0.x, b0.y, b0.z, b0.w, b1.x, b1.y, b1.z, b1.w};
  bf16x8 ov;
#pragma unroll
  for (int j = 0; j < 8; ++j)
    ov[j] = (bf16)(((x[j] - mean) * rstd) * gg[j] + bb[j]);
  *(bf16x8*)&dst[off] = ov;
}

// OUT(fp32) = x / max(||x||_2, 1e-12) per row; bf16 src
__global__ __launch_bounds__(256)
void l2norm_rows(const bf16* __restrict__ src, float* __restrict__ dst)
{
  const size_t off = (size_t)blockIdx.x * Hdim + threadIdx.x * 8;
  bf16x8 v = *(const bf16x8*)&src[off];
  float x[8], ss = 0.0f;
#pragma unroll
  for (int j = 0; j < 8; ++j) { x[j] = (float)v[j]; ss += x[j] * x[j]; }
  __shared__ float red[4];
#pragma unroll
  for (int o = 32; o; o >>= 1) ss += __shfl_xor(ss, o);
  const int w = threadIdx.x >> 6;
  if ((threadIdx.x & 63) == 0) red[w] = ss;
  __syncthreads();
  ss = red[0] + red[1] + red[2] + red[3];
  const float inv = 1.0f / fmaxf(sqrtf(ss), 1e-12f);
  float4 o0, o1;
  o0.x = x[0] * inv; o0.y = x[1] * inv; o0.z = x[2] * inv; o0.w = x[3] * inv;
  o1.x = x[4] * inv; o1.y = x[5] * inv; o1.z = x[6] * inv; o1.w = x[7] * inv;
  *(float4*)&dst[off] = o0;
  *(float4*)&dst[off + 4] = o1;
}

// ---------------------------------------------------------------------------
extern "C" void kernel_launch(void* const* d_in, const int* in_sizes, int n_in,
                              void* d_out, int out_size, void* d_ws, size_t ws_size,
                              hipStream_t stream)
{
  const float* emb  = (const float*)d_in[0];
  const int*   tix  = (const int*)d_in[1];
  const float* pe   = (const float*)d_in[2];
  const float* Wqkv = (const float*)d_in[3];
  const float* Bqkv = (const float*)d_in[4];
  const float* Wout = (const float*)d_in[5];
  const float* Bout = (const float*)d_in[6];
  const float* ln1g = (const float*)d_in[7];
  const float* ln1b = (const float*)d_in[8];
  const float* Wff1 = (const float*)d_in[9];
  const float* Bff1 = (const float*)d_in[10];
  const float* Wff2 = (const float*)d_in[11];
  const float* Bff2 = (const float*)d_in[12];
  const float* ln2g = (const float*)d_in[13];
  const float* ln2b = (const float*)d_in[14];
  const float* Wte1 = (const float*)d_in[15];
  const float* Bte1 = (const float*)d_in[16];
  const float* Wte2 = (const float*)d_in[17];
  const float* Bte2 = (const float*)d_in[18];
  const float* Wpr1 = (const float*)d_in[19];
  const float* Bpr1 = (const float*)d_in[20];
  const float* Wpr2 = (const float*)d_in[21];
  const float* Bpr2 = (const float*)d_in[22];
  float* OUT = (float*)d_out;

  char* w = (char*)d_ws;
  bf16* RA   = (bf16*)(w);                 // 64 MiB
  bf16* RB   = (bf16*)(w + (64u << 20));   // 64 MiB
  bf16* QKVc = RB;
  char* ob   = (char*)d_out;
  bf16* Pc   = (bf16*)(ob);                // attn scores   [0,32M)
  bf16* VTc  = (bf16*)(ob + (32u << 20));  // V^T           [32,48M)
  bf16* R1   = (bf16*)(ob);                // attn residual [0,64M)
  bf16* F1c  = (bf16*)(ob);                // FFN hidden    [0,32M)
  // staged bf16 weight homes in d_out (see schedule at top)
  bf16* WqkvB = (bf16*)(ob + (48u << 20));
  bf16* WoutB = (bf16*)(ob + (72u << 20));
  bf16* Wff1B = (bf16*)(ob + (64u << 20));
  bf16* Wff2B = (bf16*)(ob + (96u << 20));
  bf16* WteB1 = (bf16*)(ob);
  bf16* WteB2 = (bf16*)(ob + (8u << 20));
  bf16* WprB1 = (bf16*)(ob + (16u << 20));
  bf16* WprB2 = (bf16*)(ob + (24u << 20));

  // 0. convert attention weights (d_out [48,80M) free until step 7 / FFN)
  cvt_w<<<6144, 256, 0, stream>>>(Wqkv, WqkvB);   // 6144x2048
  cvt_w<<<2048, 256, 0, stream>>>(Wout, WoutB);   // 2048x2048

  // 1. X = emb + pe[idx]
  gather_pe<<<16384, 256, 0, stream>>>(emb, tix, pe, RA);

  // 2-6. attention: 4 chunks of 8 batches (4096 rows, 64 (b,h) pairs each)
  for (int c = 0; c < 4; ++c) {
    const bf16* Xc = RA + (size_t)c * 4096 * 2048;
    bf16* Oc = RA + (size_t)c * 4096 * 2048;   // O rows alias dead X rows

    // QKVc = Xc @ Wqkv^T + Bqkv   [4096,6144]
    gemm_bt<0><<<dim3(48, 32, 1), 256, 0, stream>>>(
        Xc, 2048, 0, 0, 1, WqkvB, 2048, 0, 0, 1, QKVc, 6144, 0, 0, 1,
        Bqkv, nullptr, 0, 2048, 1.0f, 0);

    // Pc[z] = Q K^T / 16,  z = b_local*8 + h
    gemm_bt<0><<<dim3(4, 4, 64), 256, 0, stream>>>(
        QKVc, 6144, 3145728L, 256, 8,
        QKVc + 2048, 6144, 3145728L, 256, 8,
        Pc, 512, 262144L, 0, 1,
        nullptr, nullptr, 0, 256, 0.0625f, 0);

    softmax_rows<<<8192, 256, 0, stream>>>(Pc);

    transpose_v<<<dim3(4, 8, 64), 256, 0, stream>>>(QKVc, VTc);

    // Oc = Pc @ V
    gemm_bt<0><<<dim3(2, 4, 64), 256, 0, stream>>>(
        Pc, 512, 262144L, 0, 1,
        VTc, 512, 131072L, 0, 1,
        Oc, 2048, 1048576L, 256, 8,
        nullptr, nullptr, 0, 512, 1.0f, 0);
  }

  // 7. R1 = O @ Wout^T + Bout + emb(fp32 residual)   (R1 in d_out scratch)
  gemm_bt<1><<<dim3(16, 128, 1), 256, 0, stream>>>(
      RA, 2048, 0, 0, 1, WoutB, 2048, 0, 0, 1, R1, 2048, 0, 0, 1,
      Bout, emb, 2048, 2048, 1.0f, 0);

  // 7b. convert FFN weights into [64,128M) (Wout/Wqkv homes now dead)
  cvt_w<<<8192, 256, 0, stream>>>(Wff1, Wff1B);   // 8192x2048
  cvt_w<<<8192, 256, 0, stream>>>(Wff2, Wff2B);   // 2048x8192

  // 8. H1 = LN(R1) -> RA (O dead)
  ln_rows<<<16384, 256, 0, stream>>>(R1, ln1g, ln1b, RA);

  // 9-10. FFN in 8 row-chunks of 2048 rows; F1c in d_out (R1 dead); R2 -> RB
  for (int f = 0; f < 8; ++f) {
    const bf16* H1f = RA + (size_t)f * 2048 * 2048;
    bf16* R2f = RB + (size_t)f * 2048 * 2048;
    gemm_bt<0><<<dim3(64, 16, 1), 256, 0, stream>>>(
        H1f, 2048, 0, 0, 1, Wff1B, 2048, 0, 0, 1, F1c, 8192, 0, 0, 1,
        Bff1, nullptr, 0, 2048, 1.0f, 2);
    gemm_bt<0><<<dim3(16, 16, 1), 256, 0, stream>>>(
        F1c, 8192, 0, 0, 1, Wff2B, 8192, 0, 0, 1, R2f, 2048, 0, 0, 1,
        Bff2, H1f, 2048, 8192, 1.0f, 0);
  }

  // 10b. convert te/pr weights into [0,32M) (F1c dead)
  cvt_w<<<2048, 256, 0, stream>>>(Wte1, WteB1);
  cvt_w<<<2048, 256, 0, stream>>>(Wte2, WteB2);
  cvt_w<<<2048, 256, 0, stream>>>(Wpr1, WprB1);
  cvt_w<<<2048, 256, 0, stream>>>(Wpr2, WprB2);

  // 11. H2 = LN(R2) -> RA (H1 dead)
  ln_rows<<<16384, 256, 0, stream>>>(RB, ln2g, ln2b, RA);

  // 12. TM = relu(H2 @ Wte1^T + Bte1) -> RB
  gemm_bt<0><<<dim3(16, 128, 1), 256, 0, stream>>>(
      RA, 2048, 0, 0, 1, WteB1, 2048, 0, 0, 1, RB, 2048, 0, 0, 1,
      Bte1, nullptr, 0, 2048, 1.0f, 1);

  // 13. TE = TM @ Wte2^T + Bte2 -> RA
  gemm_bt<0><<<dim3(16, 128, 1), 256, 0, stream>>>(
      RB, 2048, 0, 0, 1, WteB2, 2048, 0, 0, 1, RA, 2048, 0, 0, 1,
      Bte2, nullptr, 0, 2048, 1.0f, 0);

  // 14. PM = relu(TE @ Wpr1^T + Bpr1) -> RB
  gemm_bt<0><<<dim3(16, 128, 1), 256, 0, stream>>>(
      RA, 2048, 0, 0, 1, WprB1, 2048, 0, 0, 1, RB, 2048, 0, 0, 1,
      Bpr1, nullptr, 0, 2048, 1.0f, 1);

  // 15. PR = PM @ Wpr2^T + Bpr2 -> RA
  gemm_bt<0><<<dim3(16, 128, 1), 256, 0, stream>>>(
      RB, 2048, 0, 0, 1, WprB2, 2048, 0, 0, 1, RA, 2048, 0, 0, 1,
      Bpr2, nullptr, 0, 2048, 1.0f, 0);

  // 16. OUT(fp32) = l2norm(PR)  (weights in d_out dead; full overwrite)
  l2norm_rows<<<16384, 256, 0, stream>>>(RA, OUT);
}

// Round 4
// 3518.320 us; speedup vs baseline: 1.4768x; 1.1691x over previous
//
#include <hip/hip_runtime.h>
#include <math.h>

// B=32 S=512 H=2048 NH=8 HD=256.
// R6: big GEMMs moved to gemm256 — 256x256 tile, BK=64, 512 thr (8 waves 2Mx4N),
// 8-phase schedule with counted vmcnt (T3+T4), XOR LDS swizzle via pre-swizzled
// global source (T2, rule #21), setprio around MFMA clusters (T5), XCD swizzle
// (T1). Staging legality proven: region staged only after its last reader's
// phase-exit barrier; vmcnt(4) gates at p4/p8 (2 loads/wave per half-tile).
// QK^T / PV stay on the R5 128^2 2-phase kernel (small-K, z-batched).
// Weights pre-converted fp32->bf16, staged through dead d_out regions.
// FFN now 4 chunks x 4096 rows: F1c 64MiB in d_out[0,64M), Wff1B/Wff2B at
// [64,96M)/[96,128M) (converted after step 7 frees Wqkv/Wout homes).

typedef __bf16 bf16;
typedef __bf16 bf16x8 __attribute__((ext_vector_type(8)));
typedef float f32x4 __attribute__((ext_vector_type(4)));

#define Hdim 2048

// async global->LDS, 16B per lane. LDS dest must be wave-uniform base + lane*16.
#define GLOAD_LDS16(gp, lp)                                          \
  __builtin_amdgcn_global_load_lds(                                  \
      (const __attribute__((address_space(1))) void*)(gp),           \
      (__attribute__((address_space(3))) void*)(lp), 16, 0, 0)

// ---------------------------------------------------------------------------
// gemm256: C[m,n] = act(scale*sum_k A[m,k]*W[n,k] + bias[n] + res[m,n])
// A,W bf16 row-major [M,K]/[N,K]; M,N multiples of 256; K multiple of 128.
// 256x256 tile, BK=64, 512 threads = 8 waves (2M x 4N), per-wave 128x64 out.
// LDS 128 KiB: L[buf][op][half][128*64], halves = 128 rows.
// Per row (64 bf16 = 8 slots of 16B): LDS[r][s] = G[r][s^(r&7)] (staged via
// pre-swizzled global col; read with slot ((kk>>3)|quad)^(lr&7)).
// 8 phases per iteration (2 K-tiles). Stage schedule (tiles 2i@slot0, 2i+1@
// slot1): p1,p2:(2i+1).A  p3,p4:(2i+2).B  p5,p6:(2i+2).A  p7,p8:(2i+3).B.
// vmcnt(4) gates at p4 and p8 (never 0 in steady state).
// ---------------------------------------------------------------------------

#define STG(X, OP, H)                                                         \
  {                                                                           \
    const int _buf = (X) & 1;                                                 \
    const bf16* _g = (OP) ? Wg : Ag;                                          \
    const long _ld = (OP) ? ldw : lda;                                        \
    const long _ro = (long)((H) * 128) * _ld + (long)(X) * 64;                \
    bf16* _d = &L[(((_buf * 2 + (OP)) * 2 + (H)) * 8192) + tid * 8];          \
    GLOAD_LDS16(_g + _ro, _d);                                                \
    GLOAD_LDS16(_g + _ro + 64 * _ld, _d + 4096);                              \
  }

#define PH(SLOT, Q, STAGES, GATE)                                             \
  {                                                                           \
    if ((Q) == 0) {                                                           \
      _Pragma("unroll")                                                       \
      for (int nj = 0; nj < 4; ++nj) {                                        \
        const int rb = offB[SLOT] + (rbB + nj * 16 + lr) * 64;                \
        bq[nj][0] = *(const bf16x8*)&L[rb + so0];                             \
        bq[nj][1] = *(const bf16x8*)&L[rb + so1];                             \
      }                                                                       \
    }                                                                         \
    bf16x8 a00, a01, a10, a11;                                                \
    {                                                                         \
      const int r0 = offA[SLOT] + ((Q) * 32 + lr) * 64;                       \
      a00 = *(const bf16x8*)&L[r0 + so0];                                     \
      a01 = *(const bf16x8*)&L[r0 + so1];                                     \
      a10 = *(const bf16x8*)&L[r0 + 1024 + so0];                              \
      a11 = *(const bf16x8*)&L[r0 + 1024 + so1];                              \
    }                                                                         \
    STAGES;                                                                   \
    GATE;                                                                     \
    __builtin_amdgcn_s_barrier();                                             \
    asm volatile("s_waitcnt lgkmcnt(0)" ::: "memory");                        \
    __builtin_amdgcn_sched_barrier(0);                                        \
    __builtin_amdgcn_s_setprio(1);                                            \
    _Pragma("unroll")                                                         \
    for (int nj = 0; nj < 4; ++nj) {                                          \
      acc[(Q)*2][nj]   = __builtin_amdgcn_mfma_f32_16x16x32_bf16(a00, bq[nj][0], acc[(Q)*2][nj], 0, 0, 0);   \
      acc[(Q)*2+1][nj] = __builtin_amdgcn_mfma_f32_16x16x32_bf16(a10, bq[nj][0], acc[(Q)*2+1][nj], 0, 0, 0); \
    }                                                                         \
    _Pragma("unroll")                                                         \
    for (int nj = 0; nj < 4; ++nj) {                                          \
      acc[(Q)*2][nj]   = __builtin_amdgcn_mfma_f32_16x16x32_bf16(a01, bq[nj][1], acc[(Q)*2][nj], 0, 0, 0);   \
      acc[(Q)*2+1][nj] = __builtin_amdgcn_mfma_f32_16x16x32_bf16(a11, bq[nj][1], acc[(Q)*2+1][nj], 0, 0, 0); \
    }                                                                         \
    __builtin_amdgcn_s_setprio(0);                                            \
    __builtin_amdgcn_sched_barrier(0);                                        \
    __builtin_amdgcn_s_barrier();                                             \
  }

template <int RF>
__global__ __launch_bounds__(512, 2)
void gemm256(const bf16* __restrict__ A, int lda,
             const bf16* __restrict__ W, int ldw,
             bf16* __restrict__ C, int ldc,
             const float* __restrict__ bias,
             const void* __restrict__ resp, int ldr,
             int K, float scale, int act)
{
  __shared__ bf16 L[8 * 8192];   // 128 KiB: [buf][op][half][8192]
  const int tid = threadIdx.x;

  // XCD-chunked swizzle (all call sites have nwg % 8 == 0 -> bijective)
  const int nwg = gridDim.x * gridDim.y;
  int bid = blockIdx.y * gridDim.x + blockIdx.x;
  bid = (bid & 7) * (nwg >> 3) + (bid >> 3);
  const int m0 = (bid / gridDim.x) * 256, n0 = (bid % gridDim.x) * 256;

  const int lane = tid & 63, quad = lane >> 4, lr = lane & 15;
  const int wid = tid >> 6, wm = wid >> 2, wn = wid & 3;
  const int rx = lr & 7;
  const int so0 = (quad ^ rx) * 8;     // kk=0 swizzled slot (elems)
  const int so1 = so0 ^ 32;            // kk=32: slot^4 -> elems^32
  const int rbB = (wn & 1) * 64;       // B local row base within half
  const int offA[2] = { wm * 8192, (4 + wm) * 8192 };
  const int offB[2] = { (2 + (wn >> 1)) * 8192, (6 + (wn >> 1)) * 8192 };

  // staging: thread covers rows srow, srow+64 of a 128-row half; LDS linear,
  // global col pre-swizzled so LDS[r][s] = G[r][s^(r&7)]
  const int srow = tid >> 3;
  const int scol = ((tid & 7) ^ (srow & 7)) * 8;
  const bf16* Ag = A + (size_t)(m0 + srow) * lda + scol;
  const bf16* Wg = W + (size_t)(n0 + srow) * ldw + scol;

  f32x4 acc[8][4] = {};
  bf16x8 bq[4][2];

  const int nt = K >> 6;   // K-tiles of 64; even, >= 2

  // prologue: tile0 fully + tile1's B; gate tile0 (allow last 2 stages in flight)
  STG(0, 1, 0); STG(0, 1, 1); STG(0, 0, 0); STG(0, 0, 1);
  STG(1, 1, 0); STG(1, 1, 1);
  asm volatile("s_waitcnt vmcnt(4)" ::: "memory");
  __builtin_amdgcn_s_barrier();

  for (int t0 = 0; t0 < nt; t0 += 2) {
    const int nl = (t0 + 2 < nt);
    PH(0, 0, STG(t0 + 1, 0, 0), );
    PH(0, 1, STG(t0 + 1, 0, 1), );
    PH(0, 2, if (nl) STG(t0 + 2, 1, 0), );
    PH(0, 3, if (nl) STG(t0 + 2, 1, 1),
             if (nl) { asm volatile("s_waitcnt vmcnt(4)" ::: "memory"); }
             else    { asm volatile("s_waitcnt vmcnt(0)" ::: "memory"); });
    PH(1, 0, if (nl) STG(t0 + 2, 0, 0), );
    PH(1, 1, if (nl) STG(t0 + 2, 0, 1), );
    PH(1, 2, if (nl) STG(t0 + 3, 1, 0), );
    PH(1, 3, if (nl) STG(t0 + 3, 1, 1),
             if (nl) { asm volatile("s_waitcnt vmcnt(4)" ::: "memory"); });
  }

  float bj[4];
#pragma unroll
  for (int nj = 0; nj < 4; ++nj)
    bj[nj] = bias ? bias[n0 + wn * 64 + nj * 16 + lr] : 0.0f;

#pragma unroll
  for (int mi = 0; mi < 8; ++mi) {
#pragma unroll
    for (int rr = 0; rr < 4; ++rr) {
      const int m = m0 + wm * 128 + mi * 16 + quad * 4 + rr;
#pragma unroll
      for (int nj = 0; nj < 4; ++nj) {
        const int n = n0 + wn * 64 + nj * 16 + lr;
        float v = acc[mi][nj][rr] * scale + bj[nj];
        if (resp) {
          if (RF) v += ((const float*)resp)[(size_t)m * ldr + n];
          else    v += (float)((const bf16*)resp)[(size_t)m * ldr + n];
        }
        if (act == 1) v = fmaxf(v, 0.0f);
        else if (act == 2) v = 0.5f * v * (1.0f + erff(v * 0.70710678118654752f));
        C[(size_t)m * ldc + n] = (bf16)v;
      }
    }
  }
}

// ---------------------------------------------------------------------------
// 128^2 2-phase batched GEMM (R5, verified) — kept for QK^T and PV.
// ---------------------------------------------------------------------------
template <int RF>
__global__ __launch_bounds__(256)
void gemm_bt(const bf16* __restrict__ A, int lda, long sA1, long sA2, int zdA,
             const bf16* __restrict__ W, int ldw, long sW1, long sW2, int zdW,
             bf16* __restrict__ C, int ldc, long sC1, long sC2, int zdC,
             const float* __restrict__ bias,
             const void* __restrict__ resp, int ldr,
             int K, float scale, int act)
{
  __shared__ bf16 As[2][128 * 64];
  __shared__ bf16 Ws[2][128 * 64];
  const int tid = threadIdx.x;
  const int z = blockIdx.z;
  A += (size_t)(z / zdA) * sA1 + (size_t)(z % zdA) * sA2;
  W += (size_t)(z / zdW) * sW1 + (size_t)(z % zdW) * sW2;
  C += (size_t)(z / zdC) * sC1 + (size_t)(z % zdC) * sC2;

  const int nwg = gridDim.x * gridDim.y;
  int bid = blockIdx.y * gridDim.x + blockIdx.x;
  bid = (bid & 7) * (nwg >> 3) + (bid >> 3);
  const int m0 = (bid / gridDim.x) * 128, n0 = (bid % gridDim.x) * 128;

  const int sm = tid >> 3;
  const int swz = ((tid & 7) ^ (sm & 7)) * 8;
  const int lane = tid & 63, quad = lane >> 4, lr = lane & 15;
  const int wid = tid >> 6, wm = wid >> 1, wn = wid & 1;
  const int rx = lr & 7;
  const int so0 = ((quad) ^ rx) * 8;
  const int so1 = ((quad | 4) ^ rx) * 8;

  f32x4 acc[4][4] = {};

  const bf16* Ag = A + (size_t)(m0 + sm) * lda + swz;
  const bf16* Wg = W + (size_t)(n0 + sm) * ldw + swz;

  const int nt = K >> 6;
#pragma unroll
  for (int s = 0; s < 4; ++s) {
    GLOAD_LDS16(Ag + (size_t)(s * 32) * lda, &As[0][s * 2048 + tid * 8]);
    GLOAD_LDS16(Wg + (size_t)(s * 32) * ldw, &Ws[0][s * 2048 + tid * 8]);
  }
  __syncthreads();

  for (int t = 0; t < nt; ++t) {
    const int cur = t & 1;
    if (t + 1 < nt) {
      const int k0 = (t + 1) << 6;
#pragma unroll
      for (int s = 0; s < 4; ++s) {
        GLOAD_LDS16(Ag + (size_t)(s * 32) * lda + k0, &As[cur ^ 1][s * 2048 + tid * 8]);
        GLOAD_LDS16(Wg + (size_t)(s * 32) * ldw + k0, &Ws[cur ^ 1][s * 2048 + tid * 8]);
      }
    }
    const bf16* Ab = As[cur];
    const bf16* Wb = Ws[cur];
#pragma unroll
    for (int kk = 0; kk < 2; ++kk) {
      const int so = kk ? so1 : so0;
      bf16x8 af[4], bfr[4];
#pragma unroll
      for (int i = 0; i < 4; ++i)
        af[i] = *(const bf16x8*)&Ab[(wm * 64 + i * 16 + lr) * 64 + so];
#pragma unroll
      for (int j = 0; j < 4; ++j)
        bfr[j] = *(const bf16x8*)&Wb[(wn * 64 + j * 16 + lr) * 64 + so];
#pragma unroll
      for (int i = 0; i < 4; ++i)
#pragma unroll
        for (int j = 0; j < 4; ++j)
          acc[i][j] = __builtin_amdgcn_mfma_f32_16x16x32_bf16(af[i], bfr[j], acc[i][j], 0, 0, 0);
    }
    __syncthreads();
  }

  float bj[4];
#pragma unroll
  for (int j = 0; j < 4; ++j)
    bj[j] = bias ? bias[n0 + wn * 64 + j * 16 + lr] : 0.0f;

#pragma unroll
  for (int i = 0; i < 4; ++i) {
#pragma unroll
    for (int r = 0; r < 4; ++r) {
      const int m = m0 + wm * 64 + i * 16 + quad * 4 + r;
#pragma unroll
      for (int j = 0; j < 4; ++j) {
        const int n = n0 + wn * 64 + j * 16 + lr;
        float v = acc[i][j][r] * scale + bj[j];
        if (resp) {
          if (RF) v += ((const float*)resp)[(size_t)m * ldr + n];
          else    v += (float)((const bf16*)resp)[(size_t)m * ldr + n];
        }
        if (act == 1) v = fmaxf(v, 0.0f);
        else if (act == 2) v = 0.5f * v * (1.0f + erff(v * 0.70710678118654752f));
        C[(size_t)m * ldc + n] = (bf16)v;
      }
    }
  }
}

// fp32 -> bf16 bulk convert; 8 elements/thread
__global__ __launch_bounds__(256)
void cvt_w(const float* __restrict__ src, bf16* __restrict__ dst)
{
  const size_t i = ((size_t)blockIdx.x * 256 + threadIdx.x) * 8;
  float4 a = *(const float4*)&src[i];
  float4 b = *(const float4*)&src[i + 4];
  bf16x8 o;
  o[0] = (bf16)a.x; o[1] = (bf16)a.y; o[2] = (bf16)a.z; o[3] = (bf16)a.w;
  o[4] = (bf16)b.x; o[5] = (bf16)b.y; o[6] = (bf16)b.z; o[7] = (bf16)b.w;
  *(bf16x8*)&dst[i] = o;
}

// X(bf16) = emb(fp32) + pe(fp32)[idx] — one block per token row
__global__ __launch_bounds__(256)
void gather_pe(const float* __restrict__ emb, const int* __restrict__ idx,
               const float* __restrict__ pe, bf16* __restrict__ X)
{
  const int m = blockIdx.x;
  const int p = idx[m];
  const size_t off = (size_t)m * Hdim + threadIdx.x * 8;
  const size_t poff = (size_t)p * Hdim + threadIdx.x * 8;
  float4 e0 = *(const float4*)&emb[off];
  float4 e1 = *(const float4*)&emb[off + 4];
  float4 q0 = *(const float4*)&pe[poff];
  float4 q1 = *(const float4*)&pe[poff + 4];
  bf16x8 o;
  o[0] = (bf16)(e0.x + q0.x); o[1] = (bf16)(e0.y + q0.y);
  o[2] = (bf16)(e0.z + q0.z); o[3] = (bf16)(e0.w + q0.w);
  o[4] = (bf16)(e1.x + q1.x); o[5] = (bf16)(e1.y + q1.y);
  o[6] = (bf16)(e1.z + q1.z); o[7] = (bf16)(e1.w + q1.w);
  *(bf16x8*)&X[off] = o;
}

// row-softmax over 512 cols in place (bf16); one wave per row
__global__ __launch_bounds__(256)
void softmax_rows(bf16* __restrict__ P)
{
  const int lane = threadIdx.x & 63;
  const size_t row = (size_t)blockIdx.x * 4 + (threadIdx.x >> 6);
  bf16* p = P + row * 512 + lane * 8;
  bf16x8 v = *(const bf16x8*)p;
  float x[8], mx = -1e30f;
#pragma unroll
  for (int j = 0; j < 8; ++j) { x[j] = (float)v[j]; mx = fmaxf(mx, x[j]); }
#pragma unroll
  for (int o = 32; o; o >>= 1) mx = fmaxf(mx, __shfl_xor(mx, o));
  float s = 0.0f;
#pragma unroll
  for (int j = 0; j < 8; ++j) { x[j] = expf(x[j] - mx); s += x[j]; }
#pragma unroll
  for (int o = 32; o; o >>= 1) s += __shfl_xor(s, o);
  const float inv = 1.0f / s;
  bf16x8 ov;
#pragma unroll
  for (int j = 0; j < 8; ++j) ov[j] = (bf16)(x[j] * inv);
  *(bf16x8*)p = ov;
}

// per-(b_local,h) transpose V[512,256] (bf16, row stride 6144 in QKVc) -> VT[256,512]
__global__ __launch_bounds__(256)
void transpose_v(const bf16* __restrict__ qkv, bf16* __restrict__ vt)
{
  const int z = blockIdx.z, b = z >> 3, h = z & 7;
  const unsigned short* V =
      (const unsigned short*)qkv + (size_t)b * 512 * 6144 + 4096 + h * 256;
  unsigned short* out = (unsigned short*)vt + (size_t)z * 256 * 512;
  const int d0 = blockIdx.x * 64, k0 = blockIdx.y * 64;
  __shared__ unsigned short t[64 * 65];
  const int r = threadIdx.x >> 3;
  const int c8 = (threadIdx.x & 7) * 8;
#pragma unroll
  for (int pass = 0; pass < 2; ++pass) {
    const int rr = r + pass * 32;
    uint4 u = *(const uint4*)(V + (size_t)(k0 + rr) * 6144 + d0 + c8);
    const unsigned short* ep = (const unsigned short*)&u;
#pragma unroll
    for (int j = 0; j < 8; ++j) t[(c8 + j) * 65 + rr] = ep[j];
  }
  __syncthreads();
#pragma unroll
  for (int pass = 0; pass < 2; ++pass) {
    const int dr = r + pass * 32;
    unsigned short e[8];
#pragma unroll
    for (int j = 0; j < 8; ++j) e[j] = t[dr * 65 + c8 + j];
    *(uint4*)(out + (size_t)(d0 + dr) * 512 + k0 + c8) = *(const uint4*)e;
  }
}

// LayerNorm over H=2048: bf16 src -> bf16 dst, fp32 g/b; one block per row
__global__ __launch_bounds__(256)
void ln_rows(const bf16* __restrict__ src, const float* __restrict__ g,
             const float* __restrict__ b, bf16* __restrict__ dst)
{
  const size_t off = (size_t)blockIdx.x * Hdim + threadIdx.x * 8;
  bf16x8 v = *(const bf16x8*)&src[off];
  float x[8], s = 0.0f, ss = 0.0f;
#pragma unroll
  for (int j = 0; j < 8; ++j) { x[j] = (float)v[j]; s += x[j]; ss += x[j] * x[j]; }
  __shared__ float red[8];
#pragma unroll
  for (int o = 32; o; o >>= 1) { s += __shfl_xor(s, o); ss += __shfl_xor(ss, o); }
  const int w = threadIdx.x >> 6;
  if ((threadIdx.x & 63) == 0) { red[w] = s; red[4 + w] = ss; }
  __syncthreads();
  s = red[0] + red[1] + red[2] + red[3];
  ss = red[4] + red[5] + red[6] + red[7];
  const float mean = s * (1.0f / Hdim);
  const float var = ss * (1.0f / Hdim) - mean * mean;
  const float rstd = rsqrtf(var + 1e-5f);
  float4 g0 = *(const float4*)&g[threadIdx.x * 8];
  float4 g1 = *(const float4*)&g[threadIdx.x * 8 + 4];
  float4 b0 = *(const float4*)&b[threadIdx.x * 8];
  float4 b1 = *(const float4*)&b[threadIdx.x * 8 + 4];
  const float gg[8] = {g0.x, g0.y, g0.z, g0.w, g1.x, g1.y, g1.z, g1.w};
  const float bb[8] = {b0.x, b0.y, b0.z, b0.w, b1.x, b1.y, b1.z, b1.w};
  bf16x8 ov;
#pragma unroll
  for (int j = 0; j < 8; ++j)
    ov[j] = (bf16)(((x[j] - mean) * rstd) * gg[j] + bb[j]);
  *(bf16x8*)&dst[off] = ov;
}

// OUT(fp32) = x / max(||x||_2, 1e-12) per row; bf16 src
__global__ __launch_bounds__(256)
void l2norm_rows(const bf16* __restrict__ src, float* __restrict__ dst)
{
  const size_t off = (size_t)blockIdx.x * Hdim + threadIdx.x * 8;
  bf16x8 v = *(const bf16x8*)&src[off];
  float x[8], ss = 0.0f;
#pragma unroll
  for (int j = 0; j < 8; ++j) { x[j] = (float)v[j]; ss += x[j] * x[j]; }
  __shared__ float red[4];
#pragma unroll
  for (int o = 32; o; o >>= 1) ss += __shfl_xor(ss, o);
  const int w = threadIdx.x >> 6;
  if ((threadIdx.x & 63) == 0) red[w] = ss;
  __syncthreads();
  ss = red[0] + red[1] + red[2] + red[3];
  const float inv = 1.0f / fmaxf(sqrtf(ss), 1e-12f);
  float4 o0, o1;
  o0.x = x[0] * inv; o0.y = x[1] * inv; o0.z = x[2] * inv; o0.w = x[3] * inv;
  o1.x = x[4] * inv; o1.y = x[5] * inv; o1.z = x[6] * inv; o1.w = x[7] * inv;
  *(float4*)&dst[off] = o0;
  *(float4*)&dst[off + 4] = o1;
}

// ---------------------------------------------------------------------------
extern "C" void kernel_launch(void* const* d_in, const int* in_sizes, int n_in,
                              void* d_out, int out_size, void* d_ws, size_t ws_size,
                              hipStream_t stream)
{
  const float* emb  = (const float*)d_in[0];
  const int*   tix  = (const int*)d_in[1];
  const float* pe   = (const float*)d_in[2];
  const float* Wqkv = (const float*)d_in[3];
  const float* Bqkv = (const float*)d_in[4];
  const float* Wout = (const float*)d_in[5];
  const float* Bout = (const float*)d_in[6];
  const float* ln1g = (const float*)d_in[7];
  const float* ln1b = (const float*)d_in[8];
  const float* Wff1 = (const float*)d_in[9];
  const float* Bff1 = (const float*)d_in[10];
  const float* Wff2 = (const float*)d_in[11];
  const float* Bff2 = (const float*)d_in[12];
  const float* ln2g = (const float*)d_in[13];
  const float* ln2b = (const float*)d_in[14];
  const float* Wte1 = (const float*)d_in[15];
  const float* Bte1 = (const float*)d_in[16];
  const float* Wte2 = (const float*)d_in[17];
  const float* Bte2 = (const float*)d_in[18];
  const float* Wpr1 = (const float*)d_in[19];
  const float* Bpr1 = (const float*)d_in[20];
  const float* Wpr2 = (const float*)d_in[21];
  const float* Bpr2 = (const float*)d_in[22];
  float* OUT = (float*)d_out;

  char* w = (char*)d_ws;
  bf16* RA   = (bf16*)(w);                 // 64 MiB
  bf16* RB   = (bf16*)(w + (64u << 20));   // 64 MiB
  bf16* QKVc = RB;
  char* ob   = (char*)d_out;
  bf16* Pc   = (bf16*)(ob);                // attn scores   [0,32M)
  bf16* VTc  = (bf16*)(ob + (32u << 20));  // V^T           [32,48M)
  bf16* R1   = (bf16*)(ob);                // attn residual [0,64M)
  bf16* F1c  = (bf16*)(ob);                // FFN hidden    [0,64M)
  bf16* WqkvB = (bf16*)(ob + (48u << 20));
  bf16* WoutB = (bf16*)(ob + (72u << 20));
  bf16* Wff1B = (bf16*)(ob + (64u << 20));
  bf16* Wff2B = (bf16*)(ob + (96u << 20));
  bf16* WteB1 = (bf16*)(ob);
  bf16* WteB2 = (bf16*)(ob + (8u << 20));
  bf16* WprB1 = (bf16*)(ob + (16u << 20));
  bf16* WprB2 = (bf16*)(ob + (24u << 20));

  // 0. convert attention weights (d_out [48,80M) free until step 7 / FFN)
  cvt_w<<<6144, 256, 0, stream>>>(Wqkv, WqkvB);   // 6144x2048
  cvt_w<<<2048, 256, 0, stream>>>(Wout, WoutB);   // 2048x2048

  // 1. X = emb + pe[idx]
  gather_pe<<<16384, 256, 0, stream>>>(emb, tix, pe, RA);

  // 2-6. attention: 4 chunks of 8 batches (4096 rows, 64 (b,h) pairs each)
  for (int c = 0; c < 4; ++c) {
    const bf16* Xc = RA + (size_t)c * 4096 * 2048;
    bf16* Oc = RA + (size_t)c * 4096 * 2048;   // O rows alias dead X rows

    // QKVc = Xc @ Wqkv^T + Bqkv   [4096,6144]
    gemm256<0><<<dim3(24, 16), 512, 0, stream>>>(
        Xc, 2048, WqkvB, 2048, QKVc, 6144, Bqkv, nullptr, 0, 2048, 1.0f, 0);

    // Pc[z] = Q K^T / 16,  z = b_local*8 + h
    gemm_bt<0><<<dim3(4, 4, 64), 256, 0, stream>>>(
        QKVc, 6144, 3145728L, 256, 8,
        QKVc + 2048, 6144, 3145728L, 256, 8,
        Pc, 512, 262144L, 0, 1,
        nullptr, nullptr, 0, 256, 0.0625f, 0);

    softmax_rows<<<8192, 256, 0, stream>>>(Pc);

    transpose_v<<<dim3(4, 8, 64), 256, 0, stream>>>(QKVc, VTc);

    // Oc = Pc @ V
    gemm_bt<0><<<dim3(2, 4, 64), 256, 0, stream>>>(
        Pc, 512, 262144L, 0, 1,
        VTc, 512, 131072L, 0, 1,
        Oc, 2048, 1048576L, 256, 8,
        nullptr, nullptr, 0, 512, 1.0f, 0);
  }

  // 7. R1 = O @ Wout^T + Bout + emb(fp32 residual)   (R1 in d_out scratch)
  gemm256<1><<<dim3(8, 64), 512, 0, stream>>>(
      RA, 2048, WoutB, 2048, R1, 2048, Bout, emb, 2048, 2048, 1.0f, 0);

  // 7b. convert FFN weights into [64,128M) (Wout/Wqkv homes now dead)
  cvt_w<<<8192, 256, 0, stream>>>(Wff1, Wff1B);   // 8192x2048
  cvt_w<<<8192, 256, 0, stream>>>(Wff2, Wff2B);   // 2048x8192

  // 8. H1 = LN(R1) -> RA (O dead)
  ln_rows<<<16384, 256, 0, stream>>>(R1, ln1g, ln1b, RA);

  // 9-10. FFN in 4 row-chunks of 4096 rows; F1c 64MiB in d_out (R1 dead); R2->RB
  for (int f = 0; f < 4; ++f) {
    const bf16* H1f = RA + (size_t)f * 4096 * 2048;
    bf16* R2f = RB + (size_t)f * 4096 * 2048;
    gemm256<0><<<dim3(32, 16), 512, 0, stream>>>(
        H1f, 2048, Wff1B, 2048, F1c, 8192, Bff1, nullptr, 0, 2048, 1.0f, 2);
    gemm256<0><<<dim3(8, 16), 512, 0, stream>>>(
        F1c, 8192, Wff2B, 8192, R2f, 2048, Bff2, H1f, 2048, 8192, 1.0f, 0);
  }

  // 10b. convert te/pr weights into [0,32M) (F1c dead)
  cvt_w<<<2048, 256, 0, stream>>>(Wte1, WteB1);
  cvt_w<<<2048, 256, 0, stream>>>(Wte2, WteB2);
  cvt_w<<<2048, 256, 0, stream>>>(Wpr1, WprB1);
  cvt_w<<<2048, 256, 0, stream>>>(Wpr2, WprB2);

  // 11. H2 = LN(R2) -> RA (H1 dead)
  ln_rows<<<16384, 256, 0, stream>>>(RB, ln2g, ln2b, RA);

  // 12. TM = relu(H2 @ Wte1^T + Bte1) -> RB
  gemm256<0><<<dim3(8, 64), 512, 0, stream>>>(
      RA, 2048, WteB1, 2048, RB, 2048, Bte1, nullptr, 0, 2048, 1.0f, 1);

  // 13. TE = TM @ Wte2^T + Bte2 -> RA
  gemm256<0><<<dim3(8, 64), 512, 0, stream>>>(
      RB, 2048, WteB2, 2048, RA, 2048, Bte2, nullptr, 0, 2048, 1.0f, 0);

  // 14. PM = relu(TE @ Wpr1^T + Bpr1) -> RB
  gemm256<0><<<dim3(8, 64), 512, 0, stream>>>(
      RA, 2048, WprB1, 2048, RB, 2048, Bpr1, nullptr, 0, 2048, 1.0f, 1);

  // 15. PR = PM @ Wpr2^T + Bpr2 -> RA
  gemm256<0><<<dim3(8, 64), 512, 0, stream>>>(
      RB, 2048, WprB2, 2048, RA, 2048, Bpr2, nullptr, 0, 2048, 1.0f, 0);

  // 16. OUT(fp32) = l2norm(PR)  (weights in d_out dead; full overwrite)
  l2norm_rows<<<16384, 256, 0, stream>>>(RA, OUT);
}